// Round 4
// baseline (389.967 us; speedup 1.0000x reference)
//
#include <hip/hip_runtime.h>
#include <hip/hip_bf16.h>

// GIN encoder: out = BN_train( (x + scatter_sum(x[src]->dst)) @ W^T + b ), b cancels in BN.
// N=50000, F=H=512, E=160000.
// R8: aggregate gathers from a pre-converted bf16 copy of x (xb) — halves the
//     random-gather footprint (327.7 -> 163.8 MB logical) and makes xb (51.2 MB)
//     fully L3-resident, so gather re-reads stop hitting HBM. One wave per full
//     row (64 lanes x short8 = 1024 B coalesced). fp32 accumulation kept.
//     xb aliases zb (dead before gemm writes zb); prep buffers own region.
//     gemm: R7's verified minimum 2-phase (STAGE(next); COMPUTE(cur); syncthreads).
// ws: hb[N*512 bf16] | Wb[512*512 bf16] | s1|s2|scale|shift | flag |
//     deg[N] cursor[N] offs[N+1] srcbuf[E] | union{ xb | zb }[N*512 bf16]  (~105 MB)

typedef __attribute__((ext_vector_type(8))) short short8;
typedef __attribute__((ext_vector_type(4))) float floatx4;

static __device__ __forceinline__ unsigned short f2bf(float f) {
    unsigned int u = __float_as_uint(f);
    u += 0x7FFFu + ((u >> 16) & 1u);   // round-to-nearest-even
    return (unsigned short)(u >> 16);
}

static __device__ __forceinline__ float bf2f(unsigned short v) {
    return __uint_as_float((unsigned)v << 16);
}

static __device__ __forceinline__ void gload16(const void* g, void* l) {
    __builtin_amdgcn_global_load_lds(
        (const __attribute__((address_space(1))) unsigned int*)g,
        (__attribute__((address_space(3))) unsigned int*)l, 16, 0, 0);
}

// ---- detect whether edge_index is int64 (odd int32 words all zero) or int32 ----
__global__ void detect_dtype(const int* __restrict__ ei, int* __restrict__ flag) {
    __shared__ int any_nz;
    if (threadIdx.x == 0) any_nz = 0;
    __syncthreads();
    if (ei[2 * threadIdx.x + 1] != 0) atomicOr(&any_nz, 1);
    __syncthreads();
    if (threadIdx.x == 0) *flag = (any_nz == 0) ? 1 : 0;  // 1 => int64 layout
}

static __device__ __forceinline__ void load_edge(const int* ei, int flag, int E, int e,
                                                 int& s, int& d) {
    if (flag) {
        const long long* e64 = (const long long*)ei;
        s = (int)e64[e];
        d = (int)e64[E + e];
    } else {
        s = ei[e];
        d = ei[E + e];
    }
}

// ---- W fp32 -> bf16, zero stats + deg/cursor ----
__global__ __launch_bounds__(256) void conv_w(const float* __restrict__ W,
                                              unsigned short* __restrict__ Wb,
                                              float* __restrict__ stats /*1024 floats*/,
                                              int* __restrict__ dz, int ndz) {
    int i = blockIdx.x * 256 + threadIdx.x;   // 65536 threads x 4 elems = 512*512
    float4 v = ((const float4*)W)[i];
    ushort4 u;
    u.x = f2bf(v.x); u.y = f2bf(v.y); u.z = f2bf(v.z); u.w = f2bf(v.w);
    ((ushort4*)Wb)[i] = u;
    if (blockIdx.x == 0) {
        stats[threadIdx.x] = 0.f;
        stats[256 + threadIdx.x] = 0.f;
        stats[512 + threadIdx.x] = 0.f;
        stats[768 + threadIdx.x] = 0.f;
    }
    for (int k = i; k < ndz; k += 65536) dz[k] = 0;
}

// ---- x fp32 -> bf16 (xb), streaming; 8 elems/thread ----
__global__ __launch_bounds__(256) void conv_x(const float* __restrict__ x,
                                              unsigned short* __restrict__ xb, int n8) {
    int i = blockIdx.x * 256 + threadIdx.x;
    if (i >= n8) return;
    float4 v0 = ((const float4*)x)[2 * i];
    float4 v1 = ((const float4*)x)[2 * i + 1];
    short8 o;
    o[0] = (short)f2bf(v0.x); o[1] = (short)f2bf(v0.y);
    o[2] = (short)f2bf(v0.z); o[3] = (short)f2bf(v0.w);
    o[4] = (short)f2bf(v1.x); o[5] = (short)f2bf(v1.y);
    o[6] = (short)f2bf(v1.z); o[7] = (short)f2bf(v1.w);
    ((short8*)xb)[i] = o;
}

// ---- per-dst degree count ----
__global__ __launch_bounds__(256) void deg_count(const int* __restrict__ ei,
                                                 const int* __restrict__ flag,
                                                 int* __restrict__ deg, int E, int N) {
    int e = blockIdx.x * 256 + threadIdx.x;
    if (e >= E) return;
    int s, d;
    load_edge(ei, *flag, E, e, s, d);
    if ((unsigned)d < (unsigned)N) atomicAdd(&deg[d], 1);
}

// ---- single-block exclusive scan of deg[N] -> offs[N+1] ----
__global__ __launch_bounds__(1024) void scan_deg(const int* __restrict__ deg,
                                                 int* __restrict__ offs, int N) {
    __shared__ int sums[1024];
    int t = threadIdx.x;
    int per = (N + 1023) / 1024;
    int beg = t * per, end = beg + per; if (end > N) end = N; if (beg > N) beg = N;
    int s = 0;
    for (int i = beg; i < end; ++i) s += deg[i];
    sums[t] = s;
    __syncthreads();
    for (int d = 1; d < 1024; d <<= 1) {
        int v = (t >= d) ? sums[t - d] : 0;
        __syncthreads();
        sums[t] += v;
        __syncthreads();
    }
    int run = (t > 0) ? sums[t - 1] : 0;
    for (int i = beg; i < end; ++i) { offs[i] = run; run += deg[i]; }
    if (t == 0) offs[N] = sums[1023];
}

// ---- scatter src indices into dst buckets ----
__global__ __launch_bounds__(256) void bucket_fill(const int* __restrict__ ei,
                                                   const int* __restrict__ flag,
                                                   const int* __restrict__ offs,
                                                   int* __restrict__ cursor,
                                                   int* __restrict__ srcbuf, int E, int N) {
    int e = blockIdx.x * 256 + threadIdx.x;
    if (e >= E) return;
    int s, d;
    load_edge(ei, *flag, E, e, s, d);
    if ((unsigned)d >= (unsigned)N || (unsigned)s >= (unsigned)N) return;
    int pos = offs[d] + atomicAdd(&cursor[d], 1);
    srcbuf[pos] = s;
}

// ---- h[n] = bf16( xb[n] + sum_{s in bucket(n)} xb[s] ), fp32 accum.
//      One wave per row: 64 lanes x 8 bf16 = 1024 B per row read, coalesced.
//      Gathers hit L3 (xb = 51.2 MB fully L3-resident). Unrolled x2. ----
__global__ __launch_bounds__(256) void aggregate(const unsigned short* __restrict__ xb,
                                                 const int* __restrict__ offs,
                                                 const int* __restrict__ srcbuf,
                                                 unsigned short* __restrict__ hb, int N) {
    int n = blockIdx.x * 4 + (threadIdx.x >> 6);
    if (n >= N) return;
    int lane = threadIdx.x & 63;
    short8 sv = *((const short8*)(xb + (size_t)n * 512) + lane);
    float a[8];
#pragma unroll
    for (int u = 0; u < 8; ++u) a[u] = bf2f((unsigned short)sv[u]);
    int beg = offs[n], end = offs[n + 1];
    int j = beg;
    for (; j + 2 <= end; j += 2) {
        int s0 = srcbuf[j], s1 = srcbuf[j + 1];
        short8 v0 = *((const short8*)(xb + (size_t)s0 * 512) + lane);
        short8 v1 = *((const short8*)(xb + (size_t)s1 * 512) + lane);
#pragma unroll
        for (int u = 0; u < 8; ++u)
            a[u] += bf2f((unsigned short)v0[u]) + bf2f((unsigned short)v1[u]);
    }
    if (j < end) {
        int s0 = srcbuf[j];
        short8 v0 = *((const short8*)(xb + (size_t)s0 * 512) + lane);
#pragma unroll
        for (int u = 0; u < 8; ++u) a[u] += bf2f((unsigned short)v0[u]);
    }
    short8 o;
#pragma unroll
    for (int u = 0; u < 8; ++u) o[u] = (short)f2bf(a[u]);
    *((short8*)(hb + (size_t)n * 512) + lane) = o;
}

// ---- z = h @ Wb^T (bf16 out), stats fused.
//      Minimum 2-phase pipeline (verified R7): STAGE(next) issued before
//      COMPUTE(cur), ONE full-drain __syncthreads() per K-tile. ----
__global__ __launch_bounds__(256) void gemm_bt(const unsigned short* __restrict__ hb,
                                               const unsigned short* __restrict__ Wb,
                                               unsigned short* __restrict__ zb,
                                               float* __restrict__ s1,
                                               float* __restrict__ s2, int N, int nwg) {
    __shared__ unsigned short As[2][128 * 64];   // row-major, 64 bf16 (128 B) per row
    __shared__ unsigned short Bs[2][128 * 64];
    int tid = threadIdx.x;
    int wave = tid >> 6, lane = tid & 63;
    int quad = lane >> 4, l16 = lane & 15;
    int r8 = lane >> 3;          // 0..7: row within this wave's 8-row strip
    int c8 = lane & 7;           // 0..7: 16B chunk within 128B row
    int swz = c8 ^ r8;           // XOR swizzle (applied on global side)

    // bijective XCD swizzle (m204): chunk of ~nwg/8 consecutive work ids per XCD
    int bid = blockIdx.x;
    int q = nwg >> 3, r = nwg & 7;
    int xcd = bid & 7, idx = bid >> 3;
    int wg = (xcd < r) ? (xcd * (q + 1) + idx) : (r * (q + 1) + (xcd - r) * q + idx);
    int row0 = (wg >> 2) * 128;  // col-fastest: 4 col-blocks of one A-panel adjacent
    int col0 = (wg & 3) * 128;
    int wr = (wave >> 1) * 64, wc = (wave & 1) * 64;

    floatx4 acc[4][4] = {};

    const unsigned short* aG = hb + (size_t)row0 * 512 + swz * 8;
    const unsigned short* bG = Wb + (size_t)col0 * 512 + swz * 8;

#define STAGE(nb, k0)                                                                   \
    {                                                                                   \
        _Pragma("unroll")                                                               \
        for (int p = 0; p < 4; ++p) {                                                   \
            int strip = p * 4 + wave;            /* 0..15 */                            \
            int rt = strip * 8 + r8;             /* tile row 0..127 */                  \
            /* A rows may run past N by <48: lands in Wb region (finite) — unused */    \
            gload16(aG + (size_t)rt * 512 + (k0), As[nb] + strip * 512);                \
            gload16(bG + (size_t)rt * 512 + (k0), Bs[nb] + strip * 512);                \
        }                                                                               \
    }

#define COMPUTE(nb)                                                                     \
    {                                                                                   \
        _Pragma("unroll")                                                               \
        for (int kk = 0; kk < 2; ++kk) {                                                \
            short8 af[4], bfr[4];                                                       \
            _Pragma("unroll")                                                           \
            for (int i = 0; i < 4; ++i) {                                               \
                int ch = (kk * 4 + quad) ^ (l16 & 7);                                   \
                af[i]  = *(const short8*)(As[nb] + (wr + i * 16 + l16) * 64 + ch * 8);  \
                bfr[i] = *(const short8*)(Bs[nb] + (wc + i * 16 + l16) * 64 + ch * 8);  \
            }                                                                           \
            _Pragma("unroll")                                                           \
            for (int i = 0; i < 4; ++i)                                                 \
                _Pragma("unroll")                                                       \
                for (int j = 0; j < 4; ++j)                                             \
                    acc[i][j] = __builtin_amdgcn_mfma_f32_16x16x32_bf16(af[i], bfr[j],  \
                                                                        acc[i][j], 0, 0, 0); \
        }                                                                               \
    }

    STAGE(0, 0)
    __syncthreads();                 // tile 0 fully in LDS (vmcnt(0) drain)
    int cur = 0;
#pragma unroll
    for (int t = 0; t < 7; ++t) {
        STAGE(cur ^ 1, (t + 1) * 64) // issue next tile's 8 loads...
        COMPUTE(cur)                 // ...they overlap these 32 MFMAs + ds_reads
        __syncthreads();             // drain: tile t+1 landed; all waves done with cur
        cur ^= 1;
    }
    COMPUTE(cur)                     // tile 7, no prefetch
#undef STAGE
#undef COMPUTE

    // epilogue: C/D layout col=lane&15, row=quad*4+reg; z in bf16; stats per column
    float p1[4] = {0.f, 0.f, 0.f, 0.f}, p2[4] = {0.f, 0.f, 0.f, 0.f};
#pragma unroll
    for (int i = 0; i < 4; ++i) {
        int rl = wr + i * 16 + quad * 4;
#pragma unroll
        for (int j = 0; j < 4; ++j) {
            int col = col0 + wc + j * 16 + l16;
#pragma unroll
            for (int rr = 0; rr < 4; ++rr) {
                int grow = row0 + rl + rr;
                if (grow < N) {
                    float v = acc[i][j][rr];
                    zb[(size_t)grow * 512 + col] = f2bf(v);
                    p1[j] += v;
                    p2[j] += v * v;
                }
            }
        }
    }
#pragma unroll
    for (int j = 0; j < 4; ++j) {
        p1[j] += __shfl_xor(p1[j], 16); p1[j] += __shfl_xor(p1[j], 32);
        p2[j] += __shfl_xor(p2[j], 16); p2[j] += __shfl_xor(p2[j], 32);
    }
    float* f1 = (float*)As;       // reuse LDS: 128 + 128 floats
    float* f2 = f1 + 128;
    __syncthreads();              // all waves past final COMPUTE before LDS reuse
    if (tid < 256) f1[tid] = 0.f; // zeroes both f1 and f2
    __syncthreads();
    if (quad == 0) {
#pragma unroll
        for (int j = 0; j < 4; ++j) {
            atomicAdd(&f1[wc + j * 16 + l16], p1[j]);
            atomicAdd(&f2[wc + j * 16 + l16], p2[j]);
        }
    }
    __syncthreads();
    if (tid < 128) {
        unsafeAtomicAdd(&s1[col0 + tid], f1[tid]);
        unsafeAtomicAdd(&s2[col0 + tid], f2[tid]);
    }
}

__global__ void finalize(const float* __restrict__ s1, const float* __restrict__ s2,
                         const float* __restrict__ gamma, const float* __restrict__ beta,
                         float* __restrict__ scale, float* __restrict__ shift, int N) {
    int c = threadIdx.x;  // 512
    float inv = 1.f / (float)N;
    float mean = s1[c] * inv;
    float var = s2[c] * inv - mean * mean;
    if (var < 0.f) var = 0.f;
    float sc = gamma[c] * rsqrtf(var + 1e-5f);
    scale[c] = sc;
    shift[c] = beta[c] - mean * sc;
}

// ---- out = zb * scale[col] + shift[col]; zb bf16 -> out fp32 ----
__global__ __launch_bounds__(256) void bn_apply(const ushort4* __restrict__ zb,
                                                float4* __restrict__ out,
                                                const float4* __restrict__ scale,
                                                const float4* __restrict__ shift, int n4) {
    int i = blockIdx.x * 256 + threadIdx.x;
    if (i >= n4) return;
    int c4 = i & 127;   // 512/4 groups per row
    ushort4 u = zb[i];
    float4 sc = scale[c4], sh = shift[c4];
    float4 v;
    v.x = __uint_as_float((unsigned)u.x << 16) * sc.x + sh.x;
    v.y = __uint_as_float((unsigned)u.y << 16) * sc.y + sh.y;
    v.z = __uint_as_float((unsigned)u.z << 16) * sc.z + sh.z;
    v.w = __uint_as_float((unsigned)u.w << 16) * sc.w + sh.w;
    out[i] = v;
}

extern "C" void kernel_launch(void* const* d_in, const int* in_sizes, int n_in,
                              void* d_out, int out_size, void* d_ws, size_t ws_size,
                              hipStream_t stream) {
    const float* x     = (const float*)d_in[0];
    const int*   ei    = (const int*)d_in[1];
    const float* W     = (const float*)d_in[3];
    const float* gamma = (const float*)d_in[5];
    const float* beta  = (const float*)d_in[6];
    float* out = (float*)d_out;

    int N = in_sizes[0] / 512;   // 50000
    int E = in_sizes[1] / 2;     // 160000

    char* ws = (char*)d_ws;
    size_t off = 0;
    unsigned short* hb = (unsigned short*)(ws + off); off += (size_t)N * 512 * 2;
    unsigned short* Wb = (unsigned short*)(ws + off); off += 512 * 512 * 2;
    float* s1    = (float*)(ws + off); off += 2048;
    float* s2    = (float*)(ws + off); off += 2048;
    float* scale = (float*)(ws + off); off += 2048;
    float* shift = (float*)(ws + off); off += 2048;
    int*   flag  = (int*)(ws + off);   off += 256;
    // prep buffers: own region (live until aggregate ends)
    int*   deg    = (int*)(ws + off);  off += (size_t)N * 4;   // deg+cursor contiguous
    int*   cursor = (int*)(ws + off);  off += (size_t)N * 4;   // (conv_w zeroes both)
    off = (off + 255) & ~(size_t)255;
    int*   offs   = (int*)(ws + off);  off += (size_t)(N + 1) * 4;
    off = (off + 255) & ~(size_t)255;
    int*   srcbuf = (int*)(ws + off);  off += (size_t)E * 4;
    off = (off + 255) & ~(size_t)255;
    // union: xb (conv_x..aggregate) | zb (gemm..bn_apply)
    unsigned short* xb = (unsigned short*)(ws + off);
    unsigned short* zb = (unsigned short*)(ws + off);

    int n4 = N * 128;            // float4 / ushort4 count of [N,512]
    int n8 = N * 64;             // short8 count of [N,512]
    int RB = (N + 127) / 128;    // 391 row-blocks
    int nwg = RB * 4;

    hipLaunchKernelGGL(detect_dtype, dim3(1), dim3(256), 0, stream, ei, flag);
    hipLaunchKernelGGL(conv_w, dim3(256), dim3(256), 0, stream, W, Wb, s1, deg, 2 * N);
    hipLaunchKernelGGL(conv_x, dim3((n8 + 255) / 256), dim3(256), 0, stream, x, xb, n8);
    hipLaunchKernelGGL(deg_count, dim3((E + 255) / 256), dim3(256), 0, stream, ei, flag, deg, E, N);
    hipLaunchKernelGGL(scan_deg, dim3(1), dim3(1024), 0, stream, deg, offs, N);
    hipLaunchKernelGGL(bucket_fill, dim3((E + 255) / 256), dim3(256), 0, stream,
                       ei, flag, offs, cursor, srcbuf, E, N);
    hipLaunchKernelGGL(aggregate, dim3((N + 3) / 4), dim3(256), 0, stream,
                       xb, offs, srcbuf, hb, N);
    hipLaunchKernelGGL(gemm_bt, dim3(nwg), dim3(256), 0, stream,
                       hb, Wb, zb, s1, s2, N, nwg);
    hipLaunchKernelGGL(finalize, dim3(1), dim3(512), 0, stream, s1, s2, gamma, beta, scale, shift, N);
    hipLaunchKernelGGL(bn_apply, dim3((n4 + 255) / 256), dim3(256), 0, stream,
                       (const ushort4*)zb, (float4*)out, (const float4*)scale, (const float4*)shift, n4);
}

// Round 5
// 320.482 us; speedup vs baseline: 1.2168x; 1.2168x over previous
//
#include <hip/hip_runtime.h>
#include <hip/hip_bf16.h>

// GIN encoder: out = BN_train( (x + scatter_sum(x[src]->dst)) @ W^T + b ), b cancels in BN.
// N=50000, F=H=512, E=160000.
// R9: single-block scan_deg (79 us, 0.15% occupancy, latency-bound) replaced by
//     a two-kernel grid scan: scan_blk (49 blocks LDS-scan 1024-elem chunks,
//     emit block sums) + scan_fin (wave-butterfly prefix of block sums, add).
//     Everything else unchanged from R8 (bf16 gather aggregate, 2-phase gemm).
// ws: hb[N*512 bf16] | Wb[512*512 bf16] | s1|s2|scale|shift | flag | bsum[64] |
//     deg[N] cursor[N] offs[N+1] srcbuf[E] | union{ xb | zb }[N*512 bf16]  (~105 MB)

typedef __attribute__((ext_vector_type(8))) short short8;
typedef __attribute__((ext_vector_type(4))) float floatx4;

static __device__ __forceinline__ unsigned short f2bf(float f) {
    unsigned int u = __float_as_uint(f);
    u += 0x7FFFu + ((u >> 16) & 1u);   // round-to-nearest-even
    return (unsigned short)(u >> 16);
}

static __device__ __forceinline__ float bf2f(unsigned short v) {
    return __uint_as_float((unsigned)v << 16);
}

static __device__ __forceinline__ void gload16(const void* g, void* l) {
    __builtin_amdgcn_global_load_lds(
        (const __attribute__((address_space(1))) unsigned int*)g,
        (__attribute__((address_space(3))) unsigned int*)l, 16, 0, 0);
}

// ---- detect whether edge_index is int64 (odd int32 words all zero) or int32 ----
__global__ void detect_dtype(const int* __restrict__ ei, int* __restrict__ flag) {
    __shared__ int any_nz;
    if (threadIdx.x == 0) any_nz = 0;
    __syncthreads();
    if (ei[2 * threadIdx.x + 1] != 0) atomicOr(&any_nz, 1);
    __syncthreads();
    if (threadIdx.x == 0) *flag = (any_nz == 0) ? 1 : 0;  // 1 => int64 layout
}

static __device__ __forceinline__ void load_edge(const int* ei, int flag, int E, int e,
                                                 int& s, int& d) {
    if (flag) {
        const long long* e64 = (const long long*)ei;
        s = (int)e64[e];
        d = (int)e64[E + e];
    } else {
        s = ei[e];
        d = ei[E + e];
    }
}

// ---- W fp32 -> bf16, zero stats + deg/cursor ----
__global__ __launch_bounds__(256) void conv_w(const float* __restrict__ W,
                                              unsigned short* __restrict__ Wb,
                                              float* __restrict__ stats /*1024 floats*/,
                                              int* __restrict__ dz, int ndz) {
    int i = blockIdx.x * 256 + threadIdx.x;   // 65536 threads x 4 elems = 512*512
    float4 v = ((const float4*)W)[i];
    ushort4 u;
    u.x = f2bf(v.x); u.y = f2bf(v.y); u.z = f2bf(v.z); u.w = f2bf(v.w);
    ((ushort4*)Wb)[i] = u;
    if (blockIdx.x == 0) {
        stats[threadIdx.x] = 0.f;
        stats[256 + threadIdx.x] = 0.f;
        stats[512 + threadIdx.x] = 0.f;
        stats[768 + threadIdx.x] = 0.f;
    }
    for (int k = i; k < ndz; k += 65536) dz[k] = 0;
}

// ---- x fp32 -> bf16 (xb), streaming; 8 elems/thread ----
__global__ __launch_bounds__(256) void conv_x(const float* __restrict__ x,
                                              unsigned short* __restrict__ xb, int n8) {
    int i = blockIdx.x * 256 + threadIdx.x;
    if (i >= n8) return;
    float4 v0 = ((const float4*)x)[2 * i];
    float4 v1 = ((const float4*)x)[2 * i + 1];
    short8 o;
    o[0] = (short)f2bf(v0.x); o[1] = (short)f2bf(v0.y);
    o[2] = (short)f2bf(v0.z); o[3] = (short)f2bf(v0.w);
    o[4] = (short)f2bf(v1.x); o[5] = (short)f2bf(v1.y);
    o[6] = (short)f2bf(v1.z); o[7] = (short)f2bf(v1.w);
    ((short8*)xb)[i] = o;
}

// ---- per-dst degree count ----
__global__ __launch_bounds__(256) void deg_count(const int* __restrict__ ei,
                                                 const int* __restrict__ flag,
                                                 int* __restrict__ deg, int E, int N) {
    int e = blockIdx.x * 256 + threadIdx.x;
    if (e >= E) return;
    int s, d;
    load_edge(ei, *flag, E, e, s, d);
    if ((unsigned)d < (unsigned)N) atomicAdd(&deg[d], 1);
}

// ---- grid scan, part 1: per-block LDS scan of 1024-elem chunk ----
__global__ __launch_bounds__(1024) void scan_blk(const int* __restrict__ deg,
                                                 int* __restrict__ offs,
                                                 int* __restrict__ bsum, int N) {
    __shared__ int s[1024];
    int t = threadIdx.x;
    int g = blockIdx.x * 1024 + t;
    int v = (g < N) ? deg[g] : 0;
    s[t] = v;
    __syncthreads();
    for (int d = 1; d < 1024; d <<= 1) {
        int u = (t >= d) ? s[t - d] : 0;
        __syncthreads();
        s[t] += u;
        __syncthreads();
    }
    if (g < N) offs[g] = s[t] - v;          // exclusive, missing block offset
    if (t == 1023) bsum[blockIdx.x] = s[1023];
}

// ---- grid scan, part 2: add prefix of block sums (wave-0 butterfly) ----
__global__ __launch_bounds__(1024) void scan_fin(int* __restrict__ offs,
                                                 const int* __restrict__ bsum,
                                                 int N, int nb) {
    __shared__ int sh_pre, sh_tot;
    int t = threadIdx.x, b = blockIdx.x;
    if (t < 64) {                            // one full wave; nb <= 64
        int v = (t < nb) ? bsum[t] : 0;
        int p = (t < b) ? v : 0;
#pragma unroll
        for (int d = 1; d < 64; d <<= 1) { p += __shfl_xor(p, d); v += __shfl_xor(v, d); }
        if (t == 0) { sh_pre = p; sh_tot = v; }
    }
    __syncthreads();
    int g = b * 1024 + t;
    if (g < N) offs[g] += sh_pre;
    if (b == nb - 1 && t == 0) offs[N] = sh_tot;
}

// ---- scatter src indices into dst buckets ----
__global__ __launch_bounds__(256) void bucket_fill(const int* __restrict__ ei,
                                                   const int* __restrict__ flag,
                                                   const int* __restrict__ offs,
                                                   int* __restrict__ cursor,
                                                   int* __restrict__ srcbuf, int E, int N) {
    int e = blockIdx.x * 256 + threadIdx.x;
    if (e >= E) return;
    int s, d;
    load_edge(ei, *flag, E, e, s, d);
    if ((unsigned)d >= (unsigned)N || (unsigned)s >= (unsigned)N) return;
    int pos = offs[d] + atomicAdd(&cursor[d], 1);
    srcbuf[pos] = s;
}

// ---- h[n] = bf16( xb[n] + sum_{s in bucket(n)} xb[s] ), fp32 accum.
//      One wave per row: 64 lanes x 8 bf16 = 1024 B per row read, coalesced.
//      Gathers hit L3 (xb = 51.2 MB fully L3-resident). Unrolled x2. ----
__global__ __launch_bounds__(256) void aggregate(const unsigned short* __restrict__ xb,
                                                 const int* __restrict__ offs,
                                                 const int* __restrict__ srcbuf,
                                                 unsigned short* __restrict__ hb, int N) {
    int n = blockIdx.x * 4 + (threadIdx.x >> 6);
    if (n >= N) return;
    int lane = threadIdx.x & 63;
    short8 sv = *((const short8*)(xb + (size_t)n * 512) + lane);
    float a[8];
#pragma unroll
    for (int u = 0; u < 8; ++u) a[u] = bf2f((unsigned short)sv[u]);
    int beg = offs[n], end = offs[n + 1];
    int j = beg;
    for (; j + 2 <= end; j += 2) {
        int s0 = srcbuf[j], s1 = srcbuf[j + 1];
        short8 v0 = *((const short8*)(xb + (size_t)s0 * 512) + lane);
        short8 v1 = *((const short8*)(xb + (size_t)s1 * 512) + lane);
#pragma unroll
        for (int u = 0; u < 8; ++u)
            a[u] += bf2f((unsigned short)v0[u]) + bf2f((unsigned short)v1[u]);
    }
    if (j < end) {
        int s0 = srcbuf[j];
        short8 v0 = *((const short8*)(xb + (size_t)s0 * 512) + lane);
#pragma unroll
        for (int u = 0; u < 8; ++u) a[u] += bf2f((unsigned short)v0[u]);
    }
    short8 o;
#pragma unroll
    for (int u = 0; u < 8; ++u) o[u] = (short)f2bf(a[u]);
    *((short8*)(hb + (size_t)n * 512) + lane) = o;
}

// ---- z = h @ Wb^T (bf16 out), stats fused.
//      Minimum 2-phase pipeline (verified R7): STAGE(next) issued before
//      COMPUTE(cur), ONE full-drain __syncthreads() per K-tile. ----
__global__ __launch_bounds__(256) void gemm_bt(const unsigned short* __restrict__ hb,
                                               const unsigned short* __restrict__ Wb,
                                               unsigned short* __restrict__ zb,
                                               float* __restrict__ s1,
                                               float* __restrict__ s2, int N, int nwg) {
    __shared__ unsigned short As[2][128 * 64];   // row-major, 64 bf16 (128 B) per row
    __shared__ unsigned short Bs[2][128 * 64];
    int tid = threadIdx.x;
    int wave = tid >> 6, lane = tid & 63;
    int quad = lane >> 4, l16 = lane & 15;
    int r8 = lane >> 3;          // 0..7: row within this wave's 8-row strip
    int c8 = lane & 7;           // 0..7: 16B chunk within 128B row
    int swz = c8 ^ r8;           // XOR swizzle (applied on global side)

    // bijective XCD swizzle (m204): chunk of ~nwg/8 consecutive work ids per XCD
    int bid = blockIdx.x;
    int q = nwg >> 3, r = nwg & 7;
    int xcd = bid & 7, idx = bid >> 3;
    int wg = (xcd < r) ? (xcd * (q + 1) + idx) : (r * (q + 1) + (xcd - r) * q + idx);
    int row0 = (wg >> 2) * 128;  // col-fastest: 4 col-blocks of one A-panel adjacent
    int col0 = (wg & 3) * 128;
    int wr = (wave >> 1) * 64, wc = (wave & 1) * 64;

    floatx4 acc[4][4] = {};

    const unsigned short* aG = hb + (size_t)row0 * 512 + swz * 8;
    const unsigned short* bG = Wb + (size_t)col0 * 512 + swz * 8;

#define STAGE(nb, k0)                                                                   \
    {                                                                                   \
        _Pragma("unroll")                                                               \
        for (int p = 0; p < 4; ++p) {                                                   \
            int strip = p * 4 + wave;            /* 0..15 */                            \
            int rt = strip * 8 + r8;             /* tile row 0..127 */                  \
            /* A rows may run past N by <48: lands in Wb region (finite) — unused */    \
            gload16(aG + (size_t)rt * 512 + (k0), As[nb] + strip * 512);                \
            gload16(bG + (size_t)rt * 512 + (k0), Bs[nb] + strip * 512);                \
        }                                                                               \
    }

#define COMPUTE(nb)                                                                     \
    {                                                                                   \
        _Pragma("unroll")                                                               \
        for (int kk = 0; kk < 2; ++kk) {                                                \
            short8 af[4], bfr[4];                                                       \
            _Pragma("unroll")                                                           \
            for (int i = 0; i < 4; ++i) {                                               \
                int ch = (kk * 4 + quad) ^ (l16 & 7);                                   \
                af[i]  = *(const short8*)(As[nb] + (wr + i * 16 + l16) * 64 + ch * 8);  \
                bfr[i] = *(const short8*)(Bs[nb] + (wc + i * 16 + l16) * 64 + ch * 8);  \
            }                                                                           \
            _Pragma("unroll")                                                           \
            for (int i = 0; i < 4; ++i)                                                 \
                _Pragma("unroll")                                                       \
                for (int j = 0; j < 4; ++j)                                             \
                    acc[i][j] = __builtin_amdgcn_mfma_f32_16x16x32_bf16(af[i], bfr[j],  \
                                                                        acc[i][j], 0, 0, 0); \
        }                                                                               \
    }

    STAGE(0, 0)
    __syncthreads();                 // tile 0 fully in LDS (vmcnt(0) drain)
    int cur = 0;
#pragma unroll
    for (int t = 0; t < 7; ++t) {
        STAGE(cur ^ 1, (t + 1) * 64) // issue next tile's 8 loads...
        COMPUTE(cur)                 // ...they overlap these 32 MFMAs + ds_reads
        __syncthreads();             // drain: tile t+1 landed; all waves done with cur
        cur ^= 1;
    }
    COMPUTE(cur)                     // tile 7, no prefetch
#undef STAGE
#undef COMPUTE

    // epilogue: C/D layout col=lane&15, row=quad*4+reg; z in bf16; stats per column
    float p1[4] = {0.f, 0.f, 0.f, 0.f}, p2[4] = {0.f, 0.f, 0.f, 0.f};
#pragma unroll
    for (int i = 0; i < 4; ++i) {
        int rl = wr + i * 16 + quad * 4;
#pragma unroll
        for (int j = 0; j < 4; ++j) {
            int col = col0 + wc + j * 16 + l16;
#pragma unroll
            for (int rr = 0; rr < 4; ++rr) {
                int grow = row0 + rl + rr;
                if (grow < N) {
                    float v = acc[i][j][rr];
                    zb[(size_t)grow * 512 + col] = f2bf(v);
                    p1[j] += v;
                    p2[j] += v * v;
                }
            }
        }
    }
#pragma unroll
    for (int j = 0; j < 4; ++j) {
        p1[j] += __shfl_xor(p1[j], 16); p1[j] += __shfl_xor(p1[j], 32);
        p2[j] += __shfl_xor(p2[j], 16); p2[j] += __shfl_xor(p2[j], 32);
    }
    float* f1 = (float*)As;       // reuse LDS: 128 + 128 floats
    float* f2 = f1 + 128;
    __syncthreads();              // all waves past final COMPUTE before LDS reuse
    if (tid < 256) f1[tid] = 0.f; // zeroes both f1 and f2
    __syncthreads();
    if (quad == 0) {
#pragma unroll
        for (int j = 0; j < 4; ++j) {
            atomicAdd(&f1[wc + j * 16 + l16], p1[j]);
            atomicAdd(&f2[wc + j * 16 + l16], p2[j]);
        }
    }
    __syncthreads();
    if (tid < 128) {
        unsafeAtomicAdd(&s1[col0 + tid], f1[tid]);
        unsafeAtomicAdd(&s2[col0 + tid], f2[tid]);
    }
}

__global__ void finalize(const float* __restrict__ s1, const float* __restrict__ s2,
                         const float* __restrict__ gamma, const float* __restrict__ beta,
                         float* __restrict__ scale, float* __restrict__ shift, int N) {
    int c = threadIdx.x;  // 512
    float inv = 1.f / (float)N;
    float mean = s1[c] * inv;
    float var = s2[c] * inv - mean * mean;
    if (var < 0.f) var = 0.f;
    float sc = gamma[c] * rsqrtf(var + 1e-5f);
    scale[c] = sc;
    shift[c] = beta[c] - mean * sc;
}

// ---- out = zb * scale[col] + shift[col]; zb bf16 -> out fp32 ----
__global__ __launch_bounds__(256) void bn_apply(const ushort4* __restrict__ zb,
                                                float4* __restrict__ out,
                                                const float4* __restrict__ scale,
                                                const float4* __restrict__ shift, int n4) {
    int i = blockIdx.x * 256 + threadIdx.x;
    if (i >= n4) return;
    int c4 = i & 127;   // 512/4 groups per row
    ushort4 u = zb[i];
    float4 sc = scale[c4], sh = shift[c4];
    float4 v;
    v.x = __uint_as_float((unsigned)u.x << 16) * sc.x + sh.x;
    v.y = __uint_as_float((unsigned)u.y << 16) * sc.y + sh.y;
    v.z = __uint_as_float((unsigned)u.z << 16) * sc.z + sh.z;
    v.w = __uint_as_float((unsigned)u.w << 16) * sc.w + sh.w;
    out[i] = v;
}

extern "C" void kernel_launch(void* const* d_in, const int* in_sizes, int n_in,
                              void* d_out, int out_size, void* d_ws, size_t ws_size,
                              hipStream_t stream) {
    const float* x     = (const float*)d_in[0];
    const int*   ei    = (const int*)d_in[1];
    const float* W     = (const float*)d_in[3];
    const float* gamma = (const float*)d_in[5];
    const float* beta  = (const float*)d_in[6];
    float* out = (float*)d_out;

    int N = in_sizes[0] / 512;   // 50000
    int E = in_sizes[1] / 2;     // 160000

    char* ws = (char*)d_ws;
    size_t off = 0;
    unsigned short* hb = (unsigned short*)(ws + off); off += (size_t)N * 512 * 2;
    unsigned short* Wb = (unsigned short*)(ws + off); off += 512 * 512 * 2;
    float* s1    = (float*)(ws + off); off += 2048;
    float* s2    = (float*)(ws + off); off += 2048;
    float* scale = (float*)(ws + off); off += 2048;
    float* shift = (float*)(ws + off); off += 2048;
    int*   flag  = (int*)(ws + off);   off += 256;
    int*   bsum  = (int*)(ws + off);   off += 256;   // 64 block sums for grid scan
    // prep buffers: own region (live until aggregate ends)
    int*   deg    = (int*)(ws + off);  off += (size_t)N * 4;   // deg+cursor contiguous
    int*   cursor = (int*)(ws + off);  off += (size_t)N * 4;   // (conv_w zeroes both)
    off = (off + 255) & ~(size_t)255;
    int*   offs   = (int*)(ws + off);  off += (size_t)(N + 1) * 4;
    off = (off + 255) & ~(size_t)255;
    int*   srcbuf = (int*)(ws + off);  off += (size_t)E * 4;
    off = (off + 255) & ~(size_t)255;
    // union: xb (conv_x..aggregate) | zb (gemm..bn_apply)
    unsigned short* xb = (unsigned short*)(ws + off);
    unsigned short* zb = (unsigned short*)(ws + off);

    int n4 = N * 128;            // float4 / ushort4 count of [N,512]
    int n8 = N * 64;             // short8 count of [N,512]
    int RB = (N + 127) / 128;    // 391 row-blocks
    int nwg = RB * 4;
    int nb = (N + 1023) / 1024;  // 49 scan blocks (<= 64)

    hipLaunchKernelGGL(detect_dtype, dim3(1), dim3(256), 0, stream, ei, flag);
    hipLaunchKernelGGL(conv_w, dim3(256), dim3(256), 0, stream, W, Wb, s1, deg, 2 * N);
    hipLaunchKernelGGL(conv_x, dim3((n8 + 255) / 256), dim3(256), 0, stream, x, xb, n8);
    hipLaunchKernelGGL(deg_count, dim3((E + 255) / 256), dim3(256), 0, stream, ei, flag, deg, E, N);
    hipLaunchKernelGGL(scan_blk, dim3(nb), dim3(1024), 0, stream, deg, offs, bsum, N);
    hipLaunchKernelGGL(scan_fin, dim3(nb), dim3(1024), 0, stream, offs, bsum, N, nb);
    hipLaunchKernelGGL(bucket_fill, dim3((E + 255) / 256), dim3(256), 0, stream,
                       ei, flag, offs, cursor, srcbuf, E, N);
    hipLaunchKernelGGL(aggregate, dim3((N + 3) / 4), dim3(256), 0, stream,
                       xb, offs, srcbuf, hb, N);
    hipLaunchKernelGGL(gemm_bt, dim3(nwg), dim3(256), 0, stream,
                       hb, Wb, zb, s1, s2, N, nwg);
    hipLaunchKernelGGL(finalize, dim3(1), dim3(512), 0, stream, s1, s2, gamma, beta, scale, shift, N);
    hipLaunchKernelGGL(bn_apply, dim3((n4 + 255) / 256), dim3(256), 0, stream,
                       (const ushort4*)zb, (float4*)out, (const float4*)scale, (const float4*)shift, n4);
}

// Round 6
// 316.779 us; speedup vs baseline: 1.2310x; 1.0117x over previous
//
#include <hip/hip_runtime.h>
#include <hip/hip_bf16.h>

// GIN encoder: out = BN_train( (x + scatter_sum(x[src]->dst)) @ W^T + b ), b cancels in BN.
// N=50000, F=H=512, E=160000.
// R10: gemm tile 128x128 -> 256x256 (1024 thr, 16 waves 4x4, BK=64, 128KB LDS).
//      Halves total global_load_lds staged bytes (400 -> 200 MB), which R9's
//      counters showed is the critical path (HBM 14%, MfmaUtil 14.5%, staging
//      rate ~10B/cyc/CU). Per-wave compute + swizzles identical to verified R9;
//      only wave->tile decode, strip count, grid, and stat width change.
//      Everything else unchanged from R9 (grid scan, bf16 gather aggregate).
// ws: hb[N*512 bf16] | Wb[512*512 bf16] | s1|s2|scale|shift | flag | bsum[64] |
//     deg[N] cursor[N] offs[N+1] srcbuf[E] | union{ xb | zb }[N*512 bf16]  (~105 MB)

typedef __attribute__((ext_vector_type(8))) short short8;
typedef __attribute__((ext_vector_type(4))) float floatx4;

static __device__ __forceinline__ unsigned short f2bf(float f) {
    unsigned int u = __float_as_uint(f);
    u += 0x7FFFu + ((u >> 16) & 1u);   // round-to-nearest-even
    return (unsigned short)(u >> 16);
}

static __device__ __forceinline__ float bf2f(unsigned short v) {
    return __uint_as_float((unsigned)v << 16);
}

static __device__ __forceinline__ void gload16(const void* g, void* l) {
    __builtin_amdgcn_global_load_lds(
        (const __attribute__((address_space(1))) unsigned int*)g,
        (__attribute__((address_space(3))) unsigned int*)l, 16, 0, 0);
}

// ---- detect whether edge_index is int64 (odd int32 words all zero) or int32 ----
__global__ void detect_dtype(const int* __restrict__ ei, int* __restrict__ flag) {
    __shared__ int any_nz;
    if (threadIdx.x == 0) any_nz = 0;
    __syncthreads();
    if (ei[2 * threadIdx.x + 1] != 0) atomicOr(&any_nz, 1);
    __syncthreads();
    if (threadIdx.x == 0) *flag = (any_nz == 0) ? 1 : 0;  // 1 => int64 layout
}

static __device__ __forceinline__ void load_edge(const int* ei, int flag, int E, int e,
                                                 int& s, int& d) {
    if (flag) {
        const long long* e64 = (const long long*)ei;
        s = (int)e64[e];
        d = (int)e64[E + e];
    } else {
        s = ei[e];
        d = ei[E + e];
    }
}

// ---- W fp32 -> bf16, zero stats + deg/cursor ----
__global__ __launch_bounds__(256) void conv_w(const float* __restrict__ W,
                                              unsigned short* __restrict__ Wb,
                                              float* __restrict__ stats /*1024 floats*/,
                                              int* __restrict__ dz, int ndz) {
    int i = blockIdx.x * 256 + threadIdx.x;   // 65536 threads x 4 elems = 512*512
    float4 v = ((const float4*)W)[i];
    ushort4 u;
    u.x = f2bf(v.x); u.y = f2bf(v.y); u.z = f2bf(v.z); u.w = f2bf(v.w);
    ((ushort4*)Wb)[i] = u;
    if (blockIdx.x == 0) {
        stats[threadIdx.x] = 0.f;
        stats[256 + threadIdx.x] = 0.f;
        stats[512 + threadIdx.x] = 0.f;
        stats[768 + threadIdx.x] = 0.f;
    }
    for (int k = i; k < ndz; k += 65536) dz[k] = 0;
}

// ---- x fp32 -> bf16 (xb), streaming; 8 elems/thread ----
__global__ __launch_bounds__(256) void conv_x(const float* __restrict__ x,
                                              unsigned short* __restrict__ xb, int n8) {
    int i = blockIdx.x * 256 + threadIdx.x;
    if (i >= n8) return;
    float4 v0 = ((const float4*)x)[2 * i];
    float4 v1 = ((const float4*)x)[2 * i + 1];
    short8 o;
    o[0] = (short)f2bf(v0.x); o[1] = (short)f2bf(v0.y);
    o[2] = (short)f2bf(v0.z); o[3] = (short)f2bf(v0.w);
    o[4] = (short)f2bf(v1.x); o[5] = (short)f2bf(v1.y);
    o[6] = (short)f2bf(v1.z); o[7] = (short)f2bf(v1.w);
    ((short8*)xb)[i] = o;
}

// ---- per-dst degree count ----
__global__ __launch_bounds__(256) void deg_count(const int* __restrict__ ei,
                                                 const int* __restrict__ flag,
                                                 int* __restrict__ deg, int E, int N) {
    int e = blockIdx.x * 256 + threadIdx.x;
    if (e >= E) return;
    int s, d;
    load_edge(ei, *flag, E, e, s, d);
    if ((unsigned)d < (unsigned)N) atomicAdd(&deg[d], 1);
}

// ---- grid scan, part 1: per-block LDS scan of 1024-elem chunk ----
__global__ __launch_bounds__(1024) void scan_blk(const int* __restrict__ deg,
                                                 int* __restrict__ offs,
                                                 int* __restrict__ bsum, int N) {
    __shared__ int s[1024];
    int t = threadIdx.x;
    int g = blockIdx.x * 1024 + t;
    int v = (g < N) ? deg[g] : 0;
    s[t] = v;
    __syncthreads();
    for (int d = 1; d < 1024; d <<= 1) {
        int u = (t >= d) ? s[t - d] : 0;
        __syncthreads();
        s[t] += u;
        __syncthreads();
    }
    if (g < N) offs[g] = s[t] - v;          // exclusive, missing block offset
    if (t == 1023) bsum[blockIdx.x] = s[1023];
}

// ---- grid scan, part 2: add prefix of block sums (wave-0 butterfly) ----
__global__ __launch_bounds__(1024) void scan_fin(int* __restrict__ offs,
                                                 const int* __restrict__ bsum,
                                                 int N, int nb) {
    __shared__ int sh_pre, sh_tot;
    int t = threadIdx.x, b = blockIdx.x;
    if (t < 64) {                            // one full wave; nb <= 64
        int v = (t < nb) ? bsum[t] : 0;
        int p = (t < b) ? v : 0;
#pragma unroll
        for (int d = 1; d < 64; d <<= 1) { p += __shfl_xor(p, d); v += __shfl_xor(v, d); }
        if (t == 0) { sh_pre = p; sh_tot = v; }
    }
    __syncthreads();
    int g = b * 1024 + t;
    if (g < N) offs[g] += sh_pre;
    if (b == nb - 1 && t == 0) offs[N] = sh_tot;
}

// ---- scatter src indices into dst buckets ----
__global__ __launch_bounds__(256) void bucket_fill(const int* __restrict__ ei,
                                                   const int* __restrict__ flag,
                                                   const int* __restrict__ offs,
                                                   int* __restrict__ cursor,
                                                   int* __restrict__ srcbuf, int E, int N) {
    int e = blockIdx.x * 256 + threadIdx.x;
    if (e >= E) return;
    int s, d;
    load_edge(ei, *flag, E, e, s, d);
    if ((unsigned)d >= (unsigned)N || (unsigned)s >= (unsigned)N) return;
    int pos = offs[d] + atomicAdd(&cursor[d], 1);
    srcbuf[pos] = s;
}

// ---- h[n] = bf16( xb[n] + sum_{s in bucket(n)} xb[s] ), fp32 accum.
//      One wave per row: 64 lanes x 8 bf16 = 1024 B per row read, coalesced.
//      Gathers hit L3 (xb = 51.2 MB fully L3-resident). Unrolled x2. ----
__global__ __launch_bounds__(256) void aggregate(const unsigned short* __restrict__ xb,
                                                 const int* __restrict__ offs,
                                                 const int* __restrict__ srcbuf,
                                                 unsigned short* __restrict__ hb, int N) {
    int n = blockIdx.x * 4 + (threadIdx.x >> 6);
    if (n >= N) return;
    int lane = threadIdx.x & 63;
    short8 sv = *((const short8*)(xb + (size_t)n * 512) + lane);
    float a[8];
#pragma unroll
    for (int u = 0; u < 8; ++u) a[u] = bf2f((unsigned short)sv[u]);
    int beg = offs[n], end = offs[n + 1];
    int j = beg;
    for (; j + 2 <= end; j += 2) {
        int s0 = srcbuf[j], s1 = srcbuf[j + 1];
        short8 v0 = *((const short8*)(xb + (size_t)s0 * 512) + lane);
        short8 v1 = *((const short8*)(xb + (size_t)s1 * 512) + lane);
#pragma unroll
        for (int u = 0; u < 8; ++u)
            a[u] += bf2f((unsigned short)v0[u]) + bf2f((unsigned short)v1[u]);
    }
    if (j < end) {
        int s0 = srcbuf[j];
        short8 v0 = *((const short8*)(xb + (size_t)s0 * 512) + lane);
#pragma unroll
        for (int u = 0; u < 8; ++u) a[u] += bf2f((unsigned short)v0[u]);
    }
    short8 o;
#pragma unroll
    for (int u = 0; u < 8; ++u) o[u] = (short)f2bf(a[u]);
    *((short8*)(hb + (size_t)n * 512) + lane) = o;
}

// ---- z = h @ Wb^T (bf16 out), stats fused. 256x256 tile, 16 waves (4x4),
//      BK=64, double-buffered 128KB LDS. Verified minimum 2-phase pipeline:
//      STAGE(next) issued before COMPUTE(cur), ONE full-drain __syncthreads()
//      per K-tile. Per-wave compute identical to the verified 128x128 kernel. ----
__global__ __launch_bounds__(1024) void gemm_bt(const unsigned short* __restrict__ hb,
                                                const unsigned short* __restrict__ Wb,
                                                unsigned short* __restrict__ zb,
                                                float* __restrict__ s1,
                                                float* __restrict__ s2, int N, int nwg) {
    __shared__ unsigned short As[2][256 * 64];   // row-major, 64 bf16 (128 B) per row
    __shared__ unsigned short Bs[2][256 * 64];
    int tid = threadIdx.x;
    int wave = tid >> 6, lane = tid & 63;        // wave 0..15
    int quad = lane >> 4, l16 = lane & 15;
    int r8 = lane >> 3;          // 0..7: row within this wave's 8-row strip
    int c8 = lane & 7;           // 0..7: 16B chunk within 128B row
    int swz = c8 ^ r8;           // XOR swizzle (applied on global side)

    // bijective XCD swizzle (m204): chunk of ~nwg/8 consecutive work ids per XCD
    int bid = blockIdx.x;
    int q = nwg >> 3, r = nwg & 7;
    int xcd = bid & 7, idx = bid >> 3;
    int wg = (xcd < r) ? (xcd * (q + 1) + idx) : (r * (q + 1) + (xcd - r) * q + idx);
    int row0 = (wg >> 1) * 256;  // col-fastest: 2 col-blocks of one A-panel adjacent
    int col0 = (wg & 1) * 256;
    int wr = (wave >> 2) * 64, wc = (wave & 3) * 64;   // 4x4 wave grid, 64x64 each

    floatx4 acc[4][4] = {};

    const unsigned short* aG = hb + (size_t)row0 * 512 + swz * 8;
    const unsigned short* bG = Wb + (size_t)col0 * 512 + swz * 8;

#define STAGE(nb, k0)                                                                   \
    {                                                                                   \
        _Pragma("unroll")                                                               \
        for (int p = 0; p < 2; ++p) {                                                   \
            int strip = p * 16 + wave;           /* 0..31 */                            \
            int rt = strip * 8 + r8;             /* tile row 0..255 */                  \
            /* A rows may run past N by <176: lands in Wb/stats region — guarded */     \
            gload16(aG + (size_t)rt * 512 + (k0), As[nb] + strip * 512);                \
            gload16(bG + (size_t)rt * 512 + (k0), Bs[nb] + strip * 512);                \
        }                                                                               \
    }

#define COMPUTE(nb)                                                                     \
    {                                                                                   \
        _Pragma("unroll")                                                               \
        for (int kk = 0; kk < 2; ++kk) {                                                \
            short8 af[4], bfr[4];                                                       \
            _Pragma("unroll")                                                           \
            for (int i = 0; i < 4; ++i) {                                               \
                int ch = (kk * 4 + quad) ^ (l16 & 7);                                   \
                af[i]  = *(const short8*)(As[nb] + (wr + i * 16 + l16) * 64 + ch * 8);  \
                bfr[i] = *(const short8*)(Bs[nb] + (wc + i * 16 + l16) * 64 + ch * 8);  \
            }                                                                           \
            _Pragma("unroll")                                                           \
            for (int i = 0; i < 4; ++i)                                                 \
                _Pragma("unroll")                                                       \
                for (int j = 0; j < 4; ++j)                                             \
                    acc[i][j] = __builtin_amdgcn_mfma_f32_16x16x32_bf16(af[i], bfr[j],  \
                                                                        acc[i][j], 0, 0, 0); \
        }                                                                               \
    }

    STAGE(0, 0)
    __syncthreads();                 // tile 0 fully in LDS (vmcnt(0) drain)
    int cur = 0;
#pragma unroll
    for (int t = 0; t < 7; ++t) {
        STAGE(cur ^ 1, (t + 1) * 64) // issue next tile's 8 loads/wave...
        COMPUTE(cur)                 // ...they overlap these 32 MFMAs + ds_reads
        __syncthreads();             // drain: tile t+1 landed; all waves done with cur
        cur ^= 1;
    }
    COMPUTE(cur)                     // tile 7, no prefetch
#undef STAGE
#undef COMPUTE

    // epilogue: C/D layout col=lane&15, row=quad*4+reg; z in bf16; stats per column
    float p1[4] = {0.f, 0.f, 0.f, 0.f}, p2[4] = {0.f, 0.f, 0.f, 0.f};
#pragma unroll
    for (int i = 0; i < 4; ++i) {
        int rl = wr + i * 16 + quad * 4;
#pragma unroll
        for (int j = 0; j < 4; ++j) {
            int col = col0 + wc + j * 16 + l16;
#pragma unroll
            for (int rr = 0; rr < 4; ++rr) {
                int grow = row0 + rl + rr;
                if (grow < N) {
                    float v = acc[i][j][rr];
                    zb[(size_t)grow * 512 + col] = f2bf(v);
                    p1[j] += v;
                    p2[j] += v * v;
                }
            }
        }
    }
#pragma unroll
    for (int j = 0; j < 4; ++j) {
        p1[j] += __shfl_xor(p1[j], 16); p1[j] += __shfl_xor(p1[j], 32);
        p2[j] += __shfl_xor(p2[j], 16); p2[j] += __shfl_xor(p2[j], 32);
    }
    float* f1 = (float*)As;       // reuse LDS: 256 + 256 floats
    float* f2 = f1 + 256;
    __syncthreads();              // all waves past final COMPUTE before LDS reuse
    if (tid < 512) f1[tid] = 0.f; // zeroes both f1 and f2
    __syncthreads();
    if (quad == 0) {
#pragma unroll
        for (int j = 0; j < 4; ++j) {
            atomicAdd(&f1[wc + j * 16 + l16], p1[j]);
            atomicAdd(&f2[wc + j * 16 + l16], p2[j]);
        }
    }
    __syncthreads();
    if (tid < 256) {
        unsafeAtomicAdd(&s1[col0 + tid], f1[tid]);
        unsafeAtomicAdd(&s2[col0 + tid], f2[tid]);
    }
}

__global__ void finalize(const float* __restrict__ s1, const float* __restrict__ s2,
                         const float* __restrict__ gamma, const float* __restrict__ beta,
                         float* __restrict__ scale, float* __restrict__ shift, int N) {
    int c = threadIdx.x;  // 512
    float inv = 1.f / (float)N;
    float mean = s1[c] * inv;
    float var = s2[c] * inv - mean * mean;
    if (var < 0.f) var = 0.f;
    float sc = gamma[c] * rsqrtf(var + 1e-5f);
    scale[c] = sc;
    shift[c] = beta[c] - mean * sc;
}

// ---- out = zb * scale[col] + shift[col]; zb bf16 -> out fp32 ----
__global__ __launch_bounds__(256) void bn_apply(const ushort4* __restrict__ zb,
                                                float4* __restrict__ out,
                                                const float4* __restrict__ scale,
                                                const float4* __restrict__ shift, int n4) {
    int i = blockIdx.x * 256 + threadIdx.x;
    if (i >= n4) return;
    int c4 = i & 127;   // 512/4 groups per row
    ushort4 u = zb[i];
    float4 sc = scale[c4], sh = shift[c4];
    float4 v;
    v.x = __uint_as_float((unsigned)u.x << 16) * sc.x + sh.x;
    v.y = __uint_as_float((unsigned)u.y << 16) * sc.y + sh.y;
    v.z = __uint_as_float((unsigned)u.z << 16) * sc.z + sh.z;
    v.w = __uint_as_float((unsigned)u.w << 16) * sc.w + sh.w;
    out[i] = v;
}

extern "C" void kernel_launch(void* const* d_in, const int* in_sizes, int n_in,
                              void* d_out, int out_size, void* d_ws, size_t ws_size,
                              hipStream_t stream) {
    const float* x     = (const float*)d_in[0];
    const int*   ei    = (const int*)d_in[1];
    const float* W     = (const float*)d_in[3];
    const float* gamma = (const float*)d_in[5];
    const float* beta  = (const float*)d_in[6];
    float* out = (float*)d_out;

    int N = in_sizes[0] / 512;   // 50000
    int E = in_sizes[1] / 2;     // 160000

    char* ws = (char*)d_ws;
    size_t off = 0;
    unsigned short* hb = (unsigned short*)(ws + off); off += (size_t)N * 512 * 2;
    unsigned short* Wb = (unsigned short*)(ws + off); off += 512 * 512 * 2;
    float* s1    = (float*)(ws + off); off += 2048;
    float* s2    = (float*)(ws + off); off += 2048;
    float* scale = (float*)(ws + off); off += 2048;
    float* shift = (float*)(ws + off); off += 2048;
    int*   flag  = (int*)(ws + off);   off += 256;
    int*   bsum  = (int*)(ws + off);   off += 256;   // 64 block sums for grid scan
    // prep buffers: own region (live until aggregate ends)
    int*   deg    = (int*)(ws + off);  off += (size_t)N * 4;   // deg+cursor contiguous
    int*   cursor = (int*)(ws + off);  off += (size_t)N * 4;   // (conv_w zeroes both)
    off = (off + 255) & ~(size_t)255;
    int*   offs   = (int*)(ws + off);  off += (size_t)(N + 1) * 4;
    off = (off + 255) & ~(size_t)255;
    int*   srcbuf = (int*)(ws + off);  off += (size_t)E * 4;
    off = (off + 255) & ~(size_t)255;
    // union: xb (conv_x..aggregate) | zb (gemm..bn_apply)
    unsigned short* xb = (unsigned short*)(ws + off);
    unsigned short* zb = (unsigned short*)(ws + off);

    int n4 = N * 128;            // float4 / ushort4 count of [N,512]
    int n8 = N * 64;             // short8 count of [N,512]
    int RB = (N + 255) / 256;    // 196 row-blocks
    int nwg = RB * 2;            // 392 workgroups (2 col-blocks of 256)
    int nb = (N + 1023) / 1024;  // 49 scan blocks (<= 64)

    hipLaunchKernelGGL(detect_dtype, dim3(1), dim3(256), 0, stream, ei, flag);
    hipLaunchKernelGGL(conv_w, dim3(256), dim3(256), 0, stream, W, Wb, s1, deg, 2 * N);
    hipLaunchKernelGGL(conv_x, dim3((n8 + 255) / 256), dim3(256), 0, stream, x, xb, n8);
    hipLaunchKernelGGL(deg_count, dim3((E + 255) / 256), dim3(256), 0, stream, ei, flag, deg, E, N);
    hipLaunchKernelGGL(scan_blk, dim3(nb), dim3(1024), 0, stream, deg, offs, bsum, N);
    hipLaunchKernelGGL(scan_fin, dim3(nb), dim3(1024), 0, stream, offs, bsum, N, nb);
    hipLaunchKernelGGL(bucket_fill, dim3((E + 255) / 256), dim3(256), 0, stream,
                       ei, flag, offs, cursor, srcbuf, E, N);
    hipLaunchKernelGGL(aggregate, dim3((N + 3) / 4), dim3(256), 0, stream,
                       xb, offs, srcbuf, hb, N);
    hipLaunchKernelGGL(gemm_bt, dim3(nwg), dim3(1024), 0, stream,
                       hb, Wb, zb, s1, s2, N, nwg);
    hipLaunchKernelGGL(finalize, dim3(1), dim3(512), 0, stream, s1, s2, gamma, beta, scale, shift, N);
    hipLaunchKernelGGL(bn_apply, dim3((n4 + 255) / 256), dim3(256), 0, stream,
                       (const ushort4*)zb, (float4*)out, (const float4*)scale, (const float4*)shift, n4);
}